// Round 1
// baseline (28542.102 us; speedup 1.0000x reference)
//
#include <hip/hip_runtime.h>

// ManyToOne GRU: N=256, L=512, I=512, H=1024.
// Strategy: per-time-step fused kernel. gates = [x_t|h] @ Bpacked^T via
// mfma_f32_16x16x32_bf16 with hi/lo split-precision (3 products) for ~fp32
// accuracy. Four accumulators per 16x16 tile: r, z (K=1536), i_n (K=512),
// h_n (K=1024). Epilogue: gate math + h_new (f32 + bf16 hi/lo planes) +
// conversion of x_{t+1} to bf16 hi/lo for the next step.
// Workspace use: ~32.5 MB.

typedef unsigned short u16;
typedef __attribute__((ext_vector_type(4))) float f32x4;
typedef __attribute__((ext_vector_type(8))) short s16x8;

constexpr int NB   = 256;   // batch (GEMM M)
constexpr int LSEQ = 512;   // sequence length
constexpr int ISZ  = 512;   // input features
constexpr int HSZ  = 1024;  // hidden (GEMM N)
constexpr int K3   = ISZ + HSZ;  // 1536

__device__ __forceinline__ u16 bf16_trunc(float f) {
    union { float f; unsigned u; } v; v.f = f;
    return (u16)(v.u >> 16);
}
__device__ __forceinline__ float bf16_up(u16 h) {
    union { float f; unsigned u; } v; v.u = ((unsigned)h) << 16;
    return v.f;
}

// ---------------------------------------------------------------- prep ----
// Pack weights gate-major: Bp[g][j][k], g=0:r, 1:z, 2:n(ih part, k<512),
// 3:n(hh part, k>=512). hi/lo bf16 planes (truncation split).
__global__ __launch_bounds__(256) void prep_kernel(
    const float* __restrict__ W_ih, const float* __restrict__ W_hh,
    const float* __restrict__ b_ih, const float* __restrict__ b_hh,
    const float* __restrict__ W_out,
    u16* __restrict__ Bp_hi, u16* __restrict__ Bp_lo,
    float* __restrict__ Wt, float4* __restrict__ bias4)
{
    int idx = blockIdx.x * 256 + threadIdx.x;
    if (idx < 4 * HSZ * K3) {
        int k = idx % K3;
        int j = (idx / K3) % HSZ;
        int g = idx / (K3 * HSZ);
        int row = (g == 0) ? j : (g == 1) ? (HSZ + j) : (2 * HSZ + j);
        bool valid;
        float w = 0.f;
        if (k < ISZ) {
            valid = (g != 3);
            if (valid) w = W_ih[row * ISZ + k];
        } else {
            valid = (g != 2);
            if (valid) w = W_hh[row * HSZ + (k - ISZ)];
        }
        if (valid) {
            u16 hi = bf16_trunc(w);
            Bp_hi[idx] = hi;
            Bp_lo[idx] = bf16_trunc(w - bf16_up(hi));
        }
    }
    if (idx < HSZ * ISZ) {           // Wt[k][i] = W_out[i][k]
        int i = idx % ISZ, k = idx / ISZ;
        Wt[idx] = W_out[i * HSZ + k];
    }
    if (idx < HSZ) {                 // packed biases per hidden col j
        bias4[idx] = make_float4(b_ih[idx] + b_hh[idx],
                                 b_ih[HSZ + idx] + b_hh[HSZ + idx],
                                 b_ih[2 * HSZ + idx],
                                 b_hh[2 * HSZ + idx]);
    }
}

// ---------------------------------------------------------------- init ----
__global__ __launch_bounds__(256) void init_kernel(
    const float* __restrict__ x, const float* __restrict__ h_in,
    u16* __restrict__ xhi0, u16* __restrict__ xlo0,
    float* __restrict__ h0f, u16* __restrict__ h0hi, u16* __restrict__ h0lo)
{
    int idx = blockIdx.x * 256 + threadIdx.x;    // 131072 threads
    {   // convert x at t=0
        int n = idx >> 9, k = idx & (ISZ - 1);
        float v = x[(long)n * (LSEQ * ISZ) + k];
        u16 hi = bf16_trunc(v);
        xhi0[idx] = hi;
        xlo0[idx] = bf16_trunc(v - bf16_up(hi));
    }
    #pragma unroll
    for (int q = 0; q < 2; ++q) {    // h0 (input h, zeros in practice)
        int e = idx * 2 + q;
        float v = h_in[e];
        u16 hi = bf16_trunc(v);
        h0f[e]  = v;
        h0hi[e] = hi;
        h0lo[e] = bf16_trunc(v - bf16_up(hi));
    }
}

// ---------------------------------------------------------------- step ----
#define MFMA3(acc, a_h, a_l, b_h, b_l)                                       \
    acc = __builtin_amdgcn_mfma_f32_16x16x32_bf16(a_h, b_h, acc, 0, 0, 0);   \
    acc = __builtin_amdgcn_mfma_f32_16x16x32_bf16(a_h, b_l, acc, 0, 0, 0);   \
    acc = __builtin_amdgcn_mfma_f32_16x16x32_bf16(a_l, b_h, acc, 0, 0, 0);

__global__ __launch_bounds__(256) void gru_step(
    const float* __restrict__ x, int t,
    const u16* __restrict__ Bp_hi, const u16* __restrict__ Bp_lo,
    const float4* __restrict__ bias4,
    const u16* __restrict__ xhi, const u16* __restrict__ xlo,
    u16* __restrict__ xhi_n, u16* __restrict__ xlo_n,
    const float* __restrict__ hf,
    const u16* __restrict__ hhi, const u16* __restrict__ hlo,
    float* __restrict__ hf_n,
    u16* __restrict__ hhi_n, u16* __restrict__ hlo_n)
{
    const int lane = threadIdx.x & 63;
    const int wv   = threadIdx.x >> 6;           // wave 0..3 -> M stripe
    const int col0 = blockIdx.x * 16;            // hidden-col tile
    const int rowb = blockIdx.y * 64 + wv * 16;  // batch-row stripe
    const int lr   = lane & 15;
    const int kg   = lane >> 4;
    const int koff = kg * 8;                     // A/B frag: k = 8*(lane>>4)+e

    f32x4 acc_r  = {0.f, 0.f, 0.f, 0.f};
    f32x4 acc_z  = acc_r, acc_in = acc_r, acc_hn = acc_r;

    const int bcol = col0 + lr;
    const u16* pBr_h = Bp_hi + (0 * HSZ + bcol) * K3 + koff;
    const u16* pBr_l = Bp_lo + (0 * HSZ + bcol) * K3 + koff;
    const u16* pBz_h = Bp_hi + (1 * HSZ + bcol) * K3 + koff;
    const u16* pBz_l = Bp_lo + (1 * HSZ + bcol) * K3 + koff;
    const u16* pBn_h = Bp_hi + (2 * HSZ + bcol) * K3 + koff;
    const u16* pBn_l = Bp_lo + (2 * HSZ + bcol) * K3 + koff;
    const u16* pBh_h = Bp_hi + (3 * HSZ + bcol) * K3 + koff;
    const u16* pBh_l = Bp_lo + (3 * HSZ + bcol) * K3 + koff;

    const u16* pAx_h = xhi + (rowb + lr) * ISZ + koff;
    const u16* pAx_l = xlo + (rowb + lr) * ISZ + koff;
    const u16* pAh_h = hhi + (rowb + lr) * HSZ + koff;
    const u16* pAh_l = hlo + (rowb + lr) * HSZ + koff;

    // x part: k in [0,512)
    #pragma unroll 4
    for (int kk = 0; kk < ISZ / 32; ++kk) {
        const int k = kk * 32;
        s16x8 ah  = *(const s16x8*)(pAx_h + k);
        s16x8 al  = *(const s16x8*)(pAx_l + k);
        s16x8 brh = *(const s16x8*)(pBr_h + k);
        s16x8 brl = *(const s16x8*)(pBr_l + k);
        s16x8 bzh = *(const s16x8*)(pBz_h + k);
        s16x8 bzl = *(const s16x8*)(pBz_l + k);
        s16x8 bnh = *(const s16x8*)(pBn_h + k);
        s16x8 bnl = *(const s16x8*)(pBn_l + k);
        MFMA3(acc_r,  ah, al, brh, brl)
        MFMA3(acc_z,  ah, al, bzh, bzl)
        MFMA3(acc_in, ah, al, bnh, bnl)
    }
    // h part: k in [512,1536)
    #pragma unroll 4
    for (int kk = 0; kk < HSZ / 32; ++kk) {
        const int k = kk * 32;
        s16x8 ah  = *(const s16x8*)(pAh_h + k);
        s16x8 al  = *(const s16x8*)(pAh_l + k);
        s16x8 brh = *(const s16x8*)(pBr_h + ISZ + k);
        s16x8 brl = *(const s16x8*)(pBr_l + ISZ + k);
        s16x8 bzh = *(const s16x8*)(pBz_h + ISZ + k);
        s16x8 bzl = *(const s16x8*)(pBz_l + ISZ + k);
        s16x8 bhh = *(const s16x8*)(pBh_h + ISZ + k);
        s16x8 bhl = *(const s16x8*)(pBh_l + ISZ + k);
        MFMA3(acc_r,  ah, al, brh, brl)
        MFMA3(acc_z,  ah, al, bzh, bzl)
        MFMA3(acc_hn, ah, al, bhh, bhl)
    }

    // epilogue: gates + h update. D layout: col=lane&15, row=(lane>>4)*4+i
    const int j = col0 + lr;
    const float4 b4 = bias4[j];
    const int nb = rowb + kg * 4;
    #pragma unroll
    for (int i = 0; i < 4; ++i) {
        const int nrow = nb + i;
        float rr  = 1.f / (1.f + __expf(-(acc_r[i] + b4.x)));
        float zz  = 1.f / (1.f + __expf(-(acc_z[i] + b4.y)));
        float pre = (acc_in[i] + b4.z) + rr * (acc_hn[i] + b4.w);
        float e2  = __expf(2.f * pre);
        float ng  = 1.f - 2.f / (e2 + 1.f);          // tanh, inf-safe
        float ho  = hf[nrow * HSZ + j];
        float hn  = (1.f - zz) * ng + zz * ho;
        hf_n[nrow * HSZ + j] = hn;
        u16 hi = bf16_trunc(hn);
        hhi_n[nrow * HSZ + j] = hi;
        hlo_n[nrow * HSZ + j] = bf16_trunc(hn - bf16_up(hi));
    }

    // convert x_{t+1} -> hi/lo for next step (spread across all 256 blocks)
    if (t + 1 < LSEQ) {
        const int bid  = blockIdx.y * gridDim.x + blockIdx.x;   // 0..255
        const int base = (bid * 256 + threadIdx.x) * 2;
        #pragma unroll
        for (int q = 0; q < 2; ++q) {
            int e = base + q;
            int n = e >> 9, k = e & (ISZ - 1);
            float v = x[(long)n * (LSEQ * ISZ) + (long)(t + 1) * ISZ + k];
            u16 hi = bf16_trunc(v);
            xhi_n[e] = hi;
            xlo_n[e] = bf16_trunc(v - bf16_up(hi));
        }
    }
}

// ---------------------------------------------------------------- head ----
// y = h_final @ W_out^T + b_out; also emits h_final into d_out.
__global__ __launch_bounds__(256) void head_kernel(
    const float* __restrict__ hfin, const float* __restrict__ Wt,
    const float* __restrict__ b_out, float* __restrict__ out)
{
    __shared__ float hrow[HSZ];
    const int n = blockIdx.x;
    const int tid = threadIdx.x;
    for (int k = tid; k < HSZ; k += 256) {
        float v = hfin[n * HSZ + k];
        hrow[k] = v;
        out[NB * ISZ + n * HSZ + k] = v;   // h_final output (offset 131072)
    }
    __syncthreads();
    for (int j = tid; j < ISZ; j += 256) {
        float acc = b_out[j];
        #pragma unroll 8
        for (int k = 0; k < HSZ; ++k)
            acc = fmaf(hrow[k], Wt[k * ISZ + j], acc);
        out[n * ISZ + j] = acc;
    }
}

// -------------------------------------------------------------- launch ----
extern "C" void kernel_launch(void* const* d_in, const int* in_sizes, int n_in,
                              void* d_out, int out_size, void* d_ws, size_t ws_size,
                              hipStream_t stream) {
    (void)in_sizes; (void)n_in; (void)out_size; (void)ws_size;
    const float* x     = (const float*)d_in[0];
    const float* h_in  = (const float*)d_in[1];
    const float* W_ih  = (const float*)d_in[2];
    const float* b_ih  = (const float*)d_in[3];
    const float* W_hh  = (const float*)d_in[4];
    const float* b_hh  = (const float*)d_in[5];
    const float* W_out = (const float*)d_in[6];
    const float* b_out = (const float*)d_in[7];
    float* out = (float*)d_out;

    char* ws = (char*)d_ws;
    size_t o = 0;
    u16*    Bp_hi = (u16*)(ws + o);   o += (size_t)4 * HSZ * K3 * 2;  // 12,582,912
    u16*    Bp_lo = (u16*)(ws + o);   o += (size_t)4 * HSZ * K3 * 2;  // 12,582,912
    float*  Wt    = (float*)(ws + o); o += (size_t)HSZ * ISZ * 4;     //  2,097,152
    float4* bias4 = (float4*)(ws + o); o += (size_t)HSZ * 16;         //     16,384
    float* hf[2]; u16 *hhi[2], *hlo[2], *xhi[2], *xlo[2];
    for (int b = 0; b < 2; ++b) { hf[b]  = (float*)(ws + o); o += (size_t)NB * HSZ * 4; }
    for (int b = 0; b < 2; ++b) { hhi[b] = (u16*)(ws + o);   o += (size_t)NB * HSZ * 2; }
    for (int b = 0; b < 2; ++b) { hlo[b] = (u16*)(ws + o);   o += (size_t)NB * HSZ * 2; }
    for (int b = 0; b < 2; ++b) { xhi[b] = (u16*)(ws + o);   o += (size_t)NB * ISZ * 2; }
    for (int b = 0; b < 2; ++b) { xlo[b] = (u16*)(ws + o);   o += (size_t)NB * ISZ * 2; }
    // total ~32.5 MB

    prep_kernel<<<(4 * HSZ * K3) / 256, 256, 0, stream>>>(
        W_ih, W_hh, b_ih, b_hh, W_out, Bp_hi, Bp_lo, Wt, bias4);
    init_kernel<<<(NB * ISZ) / 256, 256, 0, stream>>>(
        x, h_in, xhi[0], xlo[0], hf[0], hhi[0], hlo[0]);

    for (int t = 0; t < LSEQ; ++t) {
        const int cur = t & 1, nxt = cur ^ 1;
        gru_step<<<dim3(HSZ / 16, NB / 64), 256, 0, stream>>>(
            x, t, Bp_hi, Bp_lo, bias4,
            xhi[cur], xlo[cur], xhi[nxt], xlo[nxt],
            hf[cur], hhi[cur], hlo[cur],
            hf[nxt], hhi[nxt], hlo[nxt]);
    }
    // after t=511, final h is in buffer 0
    head_kernel<<<NB, 256, 0, stream>>>(hf[0], Wt, b_out, out);
}

// Round 2
// 12438.199 us; speedup vs baseline: 2.2947x; 2.2947x over previous
//
#include <hip/hip_runtime.h>

// ManyToOne GRU: N=256, L=512, I=512, H=1024.
// Round 1: per-step kernel with LDS-staged weights.
//  - B (weights) pre-packed into fragment-native 1KB panels [kg:4][col:16][8e]
//    (no padding zeros: r,z use K=1536; n uses x-part 512 + h-part 1024).
//  - Double-buffered global_load_lds staging: B read ONCE per WG per step
//    (74 MB/step vs round-0's ~295 MB).
//  - XCD-aware block swizzle: col-tile c resident on XCD c>>3 (B slice 2.25MB
//    + A 1.5MB fits 4MB per-XCD L2).
//  - Numerics identical to round 0: bf16 hi/lo split, 3-product MFMA.

typedef unsigned short u16;
typedef unsigned int   u32;
typedef __attribute__((ext_vector_type(4))) float f32x4;
typedef __attribute__((ext_vector_type(8))) short s16x8;

constexpr int NB   = 256;
constexpr int LSEQ = 512;
constexpr int ISZ  = 512;
constexpr int HSZ  = 1024;

constexpr int KB_X   = 16;                 // 32-k blocks from x (512)
constexpr int KB_TOT = 48;                 // + 32 blocks from h (1024)
constexpr int PANEL  = 1024;               // bytes: 4 kg * 16 col * 8 e * 2 B
constexpr int KBBYTES   = 3 * 2 * PANEL;   // 6144 per k-block (3 planes, hi/lo)
constexpr int TILEBYTES = KB_TOT * KBBYTES;    // 294912 per 16-col tile
constexpr int GROUPS = 12, GKB = 4;
constexpr int GBYTES = GKB * KBBYTES;          // 24576 staged per group

__device__ __forceinline__ u16 bf16_trunc(float f) {
    union { float f; unsigned u; } v; v.f = f;
    return (u16)(v.u >> 16);
}
__device__ __forceinline__ float bf16_up(u16 h) {
    union { float f; unsigned u; } v; v.u = ((unsigned)h) << 16;
    return v.f;
}

#define GLL16(g, l) __builtin_amdgcn_global_load_lds(                          \
    (const __attribute__((address_space(1))) u32*)(g),                         \
    (__attribute__((address_space(3))) u32*)(l), 16, 0, 0)

// ---------------------------------------------------------------- prep ----
// Pack weights into panel layout:
//   u16 offset within tile c: kb*3072 + (p*2+hl)*512 + kg*128 + col*8 + e
//   kb<16: x-part, planes (r,z,ni) from W_ih; kb>=16: h-part (r,z,nh) from W_hh.
// Also: Wt (W_out^T) and fused bias4.
__global__ __launch_bounds__(256) void prep_kernel(
    const float* __restrict__ W_ih, const float* __restrict__ W_hh,
    const float* __restrict__ b_ih, const float* __restrict__ b_hh,
    const float* __restrict__ W_out,
    u16* __restrict__ Bws, float* __restrict__ Wt, float4* __restrict__ bias4)
{
    int idx = blockIdx.x * 256 + threadIdx.x;
    if (idx < 64 * KB_TOT * 3072) {
        int c   = idx / (KB_TOT * 3072);
        int r1  = idx % (KB_TOT * 3072);
        int kb  = r1 / 3072;
        int r2  = r1 % 3072;
        int ph  = r2 / 512;          // p*2 + hl
        int p   = ph >> 1, hl = ph & 1;
        int r3  = r2 % 512;
        int kg  = r3 / 128;
        int col = (r3 / 8) % 16;
        int e   = r3 % 8;
        int kloc = kg * 8 + e;
        int gcol = c * 16 + col;
        float w;
        if (kb < KB_X) w = W_ih[(p * HSZ + gcol) * ISZ + kb * 32 + kloc];
        else           w = W_hh[(p * HSZ + gcol) * HSZ + (kb - KB_X) * 32 + kloc];
        u16 hi = bf16_trunc(w);
        Bws[idx] = hl ? bf16_trunc(w - bf16_up(hi)) : hi;
    }
    if (idx < HSZ * ISZ) {           // Wt[k][i] = W_out[i][k]
        int i = idx % ISZ, k = idx / ISZ;
        Wt[idx] = W_out[i * HSZ + k];
    }
    if (idx < HSZ) {
        bias4[idx] = make_float4(b_ih[idx] + b_hh[idx],
                                 b_ih[HSZ + idx] + b_hh[HSZ + idx],
                                 b_ih[2 * HSZ + idx],
                                 b_hh[2 * HSZ + idx]);
    }
}

// ---------------------------------------------------------------- init ----
__global__ __launch_bounds__(256) void init_kernel(
    const float* __restrict__ x, const float* __restrict__ h_in,
    u16* __restrict__ xhi0, u16* __restrict__ xlo0,
    float* __restrict__ h0f, u16* __restrict__ h0hi, u16* __restrict__ h0lo)
{
    int idx = blockIdx.x * 256 + threadIdx.x;    // 131072 threads
    {
        int n = idx >> 9, k = idx & (ISZ - 1);
        float v = x[(long)n * (LSEQ * ISZ) + k];
        u16 hi = bf16_trunc(v);
        xhi0[idx] = hi;
        xlo0[idx] = bf16_trunc(v - bf16_up(hi));
    }
    #pragma unroll
    for (int q = 0; q < 2; ++q) {
        int e = idx * 2 + q;
        float v = h_in[e];
        u16 hi = bf16_trunc(v);
        h0f[e]  = v;
        h0hi[e] = hi;
        h0lo[e] = bf16_trunc(v - bf16_up(hi));
    }
}

// ---------------------------------------------------------------- step ----
#define MFMA3(acc, a_h, a_l, b_h, b_l)                                       \
    acc = __builtin_amdgcn_mfma_f32_16x16x32_bf16(a_h, b_h, acc, 0, 0, 0);   \
    acc = __builtin_amdgcn_mfma_f32_16x16x32_bf16(a_h, b_l, acc, 0, 0, 0);   \
    acc = __builtin_amdgcn_mfma_f32_16x16x32_bf16(a_l, b_h, acc, 0, 0, 0);

__global__ __launch_bounds__(256, 1) void gru_step(
    const float* __restrict__ x, int t,
    const u16* __restrict__ Bws, const float4* __restrict__ bias4,
    const u16* __restrict__ xhi, const u16* __restrict__ xlo,
    u16* __restrict__ xhi_n, u16* __restrict__ xlo_n,
    const float* __restrict__ hf,
    const u16* __restrict__ hhi, const u16* __restrict__ hlo,
    float* __restrict__ hf_n,
    u16* __restrict__ hhi_n, u16* __restrict__ hlo_n)
{
    __shared__ u32 ldsw[2 * GBYTES / 4];     // 48 KiB double buffer
    char* lds = (char*)ldsw;

    const int tid  = threadIdx.x;
    const int lane = tid & 63;
    const int wv   = tid >> 6;
    const int raw  = blockIdx.x;             // 0..255
    // XCD-aware decode: col-tile c pinned to XCD raw&7
    const int c    = (raw & 7) * 8 + ((raw >> 3) & 7);   // 0..63
    const int m    = raw >> 6;                           // 0..3
    const int col0 = c * 16;
    const int rowb = m * 64 + wv * 16;
    const int lr   = lane & 15;
    const int kg   = lane >> 4;
    const int koff = kg * 8;
    const int fro  = kg * 256 + lr * 16;     // frag offset within 1KB panel

    const char* tsrc = (const char*)Bws + (size_t)c * TILEBYTES;

    f32x4 acc_r  = {0.f, 0.f, 0.f, 0.f};
    f32x4 acc_z  = acc_r, acc_in = acc_r, acc_hn = acc_r;

    const u16* pAx_h = xhi + (rowb + lr) * ISZ + koff;
    const u16* pAx_l = xlo + (rowb + lr) * ISZ + koff;
    const u16* pAh_h = hhi + (rowb + lr) * HSZ + koff;
    const u16* pAh_l = hlo + (rowb + lr) * HSZ + koff;

    // stage group 0
    {
        const char* s = tsrc;
        char* d = lds;
        #pragma unroll
        for (int i = 0; i < 6; ++i) {
            int seg = i * 4 + wv;
            GLL16(s + seg * 1024 + lane * 16, d + seg * 1024);
        }
    }

    for (int g = 0; g < GROUPS; ++g) {
        __syncthreads();                     // staged buf[g&1] visible
        if (g + 1 < GROUPS) {
            const char* s = tsrc + (g + 1) * GBYTES;
            char* d = lds + ((g + 1) & 1) * GBYTES;
            #pragma unroll
            for (int i = 0; i < 6; ++i) {
                int seg = i * 4 + wv;
                GLL16(s + seg * 1024 + lane * 16, d + seg * 1024);
            }
        }
        const char* buf = lds + (g & 1) * GBYTES;
        if (g < 4) {
            // x-part: planes r, z, ni
            #pragma unroll
            for (int kl = 0; kl < 4; ++kl) {
                const int k = (g * 4 + kl) * 32;
                s16x8 ah = *(const s16x8*)(pAx_h + k);
                s16x8 al = *(const s16x8*)(pAx_l + k);
                const char* pb = buf + kl * KBBYTES;
                s16x8 brh = *(const s16x8*)(pb + 0 * 2048 + fro);
                s16x8 brl = *(const s16x8*)(pb + 0 * 2048 + 1024 + fro);
                s16x8 bzh = *(const s16x8*)(pb + 1 * 2048 + fro);
                s16x8 bzl = *(const s16x8*)(pb + 1 * 2048 + 1024 + fro);
                s16x8 bnh = *(const s16x8*)(pb + 2 * 2048 + fro);
                s16x8 bnl = *(const s16x8*)(pb + 2 * 2048 + 1024 + fro);
                MFMA3(acc_r,  ah, al, brh, brl)
                MFMA3(acc_z,  ah, al, bzh, bzl)
                MFMA3(acc_in, ah, al, bnh, bnl)
            }
        } else {
            // h-part: planes r, z, nh
            #pragma unroll
            for (int kl = 0; kl < 4; ++kl) {
                const int k = ((g - 4) * 4 + kl) * 32;
                s16x8 ah = *(const s16x8*)(pAh_h + k);
                s16x8 al = *(const s16x8*)(pAh_l + k);
                const char* pb = buf + kl * KBBYTES;
                s16x8 brh = *(const s16x8*)(pb + 0 * 2048 + fro);
                s16x8 brl = *(const s16x8*)(pb + 0 * 2048 + 1024 + fro);
                s16x8 bzh = *(const s16x8*)(pb + 1 * 2048 + fro);
                s16x8 bzl = *(const s16x8*)(pb + 1 * 2048 + 1024 + fro);
                s16x8 bhh = *(const s16x8*)(pb + 2 * 2048 + fro);
                s16x8 bhl = *(const s16x8*)(pb + 2 * 2048 + 1024 + fro);
                MFMA3(acc_r,  ah, al, brh, brl)
                MFMA3(acc_z,  ah, al, bzh, bzl)
                MFMA3(acc_hn, ah, al, bhh, bhl)
            }
        }
    }

    // epilogue: D layout col=lane&15, row=(lane>>4)*4+i
    const int j  = col0 + lr;
    const float4 b4 = bias4[j];
    const int nb = rowb + kg * 4;
    #pragma unroll
    for (int i = 0; i < 4; ++i) {
        const int nrow = nb + i;
        float rr  = 1.f / (1.f + __expf(-(acc_r[i] + b4.x)));
        float zz  = 1.f / (1.f + __expf(-(acc_z[i] + b4.y)));
        float pre = (acc_in[i] + b4.z) + rr * (acc_hn[i] + b4.w);
        float e2  = __expf(2.f * pre);
        float ng  = 1.f - 2.f / (e2 + 1.f);
        float ho  = hf[nrow * HSZ + j];
        float hn  = (1.f - zz) * ng + zz * ho;
        hf_n[nrow * HSZ + j] = hn;
        u16 hi = bf16_trunc(hn);
        hhi_n[nrow * HSZ + j] = hi;
        hlo_n[nrow * HSZ + j] = bf16_trunc(hn - bf16_up(hi));
    }

    // convert x_{t+1} for next step (raw bid spreads work over 256 blocks)
    if (t + 1 < LSEQ) {
        const int base = (raw * 256 + tid) * 2;
        #pragma unroll
        for (int q = 0; q < 2; ++q) {
            int e = base + q;
            int n = e >> 9, k = e & (ISZ - 1);
            float v = x[(long)n * (LSEQ * ISZ) + (long)(t + 1) * ISZ + k];
            u16 hi = bf16_trunc(v);
            xhi_n[e] = hi;
            xlo_n[e] = bf16_trunc(v - bf16_up(hi));
        }
    }
}

// ---------------------------------------------------------------- head ----
__global__ __launch_bounds__(256) void head_kernel(
    const float* __restrict__ hfin, const float* __restrict__ Wt,
    const float* __restrict__ b_out, float* __restrict__ out)
{
    __shared__ float hrow[HSZ];
    const int n = blockIdx.x;
    const int tid = threadIdx.x;
    for (int k = tid; k < HSZ; k += 256) {
        float v = hfin[n * HSZ + k];
        hrow[k] = v;
        out[NB * ISZ + n * HSZ + k] = v;
    }
    __syncthreads();
    for (int j = tid; j < ISZ; j += 256) {
        float acc = b_out[j];
        #pragma unroll 8
        for (int k = 0; k < HSZ; ++k)
            acc = fmaf(hrow[k], Wt[k * ISZ + j], acc);
        out[n * ISZ + j] = acc;
    }
}

// -------------------------------------------------------------- launch ----
extern "C" void kernel_launch(void* const* d_in, const int* in_sizes, int n_in,
                              void* d_out, int out_size, void* d_ws, size_t ws_size,
                              hipStream_t stream) {
    (void)in_sizes; (void)n_in; (void)out_size; (void)ws_size;
    const float* x     = (const float*)d_in[0];
    const float* h_in  = (const float*)d_in[1];
    const float* W_ih  = (const float*)d_in[2];
    const float* b_ih  = (const float*)d_in[3];
    const float* W_hh  = (const float*)d_in[4];
    const float* b_hh  = (const float*)d_in[5];
    const float* W_out = (const float*)d_in[6];
    const float* b_out = (const float*)d_in[7];
    float* out = (float*)d_out;

    char* ws = (char*)d_ws;
    size_t o = 0;
    u16*    Bws   = (u16*)(ws + o);    o += (size_t)64 * TILEBYTES;   // 18,874,368
    float*  Wt    = (float*)(ws + o);  o += (size_t)HSZ * ISZ * 4;    //  2,097,152
    float4* bias4 = (float4*)(ws + o); o += (size_t)HSZ * 16;         //     16,384
    float* hf[2]; u16 *hhi[2], *hlo[2], *xhi[2], *xlo[2];
    for (int b = 0; b < 2; ++b) { hf[b]  = (float*)(ws + o); o += (size_t)NB * HSZ * 4; }
    for (int b = 0; b < 2; ++b) { hhi[b] = (u16*)(ws + o);   o += (size_t)NB * HSZ * 2; }
    for (int b = 0; b < 2; ++b) { hlo[b] = (u16*)(ws + o);   o += (size_t)NB * HSZ * 2; }
    for (int b = 0; b < 2; ++b) { xhi[b] = (u16*)(ws + o);   o += (size_t)NB * ISZ * 2; }
    for (int b = 0; b < 2; ++b) { xlo[b] = (u16*)(ws + o);   o += (size_t)NB * ISZ * 2; }
    // total ~24.6 MB

    prep_kernel<<<(64 * KB_TOT * 3072) / 256, 256, 0, stream>>>(
        W_ih, W_hh, b_ih, b_hh, W_out, Bws, Wt, bias4);
    init_kernel<<<(NB * ISZ) / 256, 256, 0, stream>>>(
        x, h_in, xhi[0], xlo[0], hf[0], hhi[0], hlo[0]);

    for (int t = 0; t < LSEQ; ++t) {
        const int cur = t & 1, nxt = cur ^ 1;
        gru_step<<<256, 256, 0, stream>>>(
            x, t, Bws, bias4,
            xhi[cur], xlo[cur], xhi[nxt], xlo[nxt],
            hf[cur], hhi[cur], hlo[cur],
            hf[nxt], hhi[nxt], hlo[nxt]);
    }
    head_kernel<<<NB, 256, 0, stream>>>(hf[0], Wt, b_out, out);
}